// Round 8
// baseline (594.086 us; speedup 1.0000x reference)
//
#include <hip/hip_runtime.h>
#include <hip/hip_bf16.h>
#include <hip/hip_fp16.h>

#define NFEAT  128
#define HC     64
#define HEADS  4
#define NHID   16
#define NCLASS 40
#define NEG    0.2f
#define BN_EPS 1e-5f

#define BK_SH   9          // 512 nodes per bucket
#define CHUNK   8192       // edges per histogram/scatter workgroup
#define STAGE   12288      // LDS staging capacity in k_build

typedef _Float16 half8_t __attribute__((ext_vector_type(8)));
typedef _Float16 half4_t __attribute__((ext_vector_type(4)));
typedef float    f32x4_t __attribute__((ext_vector_type(4)));

__device__ __forceinline__ float leaky(float a) { return (a > 0.f) ? a : NEG * a; }

// ---------------------------------------------------------------------------
// Kernel 1 (MFMA): h1 = x @ W1 via v_mfma_f32_16x16x32_f16.
// ---------------------------------------------------------------------------
__global__ __launch_bounds__(256) void k_gemm1(
    const float* __restrict__ x, const float* __restrict__ W1,
    const float* __restrict__ att_s, const float* __restrict__ att_d,
    __half* __restrict__ h1, float* __restrict__ as1, float* __restrict__ ad1,
    int n)
{
    const int wave = threadIdx.x >> 6, lane = threadIdx.x & 63;
    const int quad = lane >> 4, l16 = lane & 15;

    half8_t bfrag[4][4];
    #pragma unroll
    for (int ks = 0; ks < 4; ++ks)
        #pragma unroll
        for (int ct = 0; ct < 4; ++ct)
            #pragma unroll
            for (int j = 0; j < 8; ++j)
                bfrag[ks][ct][j] =
                    (_Float16)W1[(ks * 32 + quad * 8 + j) * HC + ct * 16 + l16];

    float avs[4], avd[4];
    #pragma unroll
    for (int ct = 0; ct < 4; ++ct) {
        avs[ct] = att_s[ct * 16 + l16];
        avd[ct] = att_d[ct * 16 + l16];
    }

    const int nslab = (n + 15) >> 4;
    for (int slab = blockIdx.x * 4 + wave; slab < nslab; slab += gridDim.x * 4) {
        const int rowbase = slab * 16;
        const int arow = min(rowbase + l16, n - 1);
        const float* xp = x + (size_t)arow * NFEAT;

        f32x4_t acc[4] = {{0.f,0.f,0.f,0.f},{0.f,0.f,0.f,0.f},
                          {0.f,0.f,0.f,0.f},{0.f,0.f,0.f,0.f}};
        #pragma unroll
        for (int ks = 0; ks < 4; ++ks) {
            const float4 xa = *(const float4*)(xp + ks * 32 + quad * 8);
            const float4 xb = *(const float4*)(xp + ks * 32 + quad * 8 + 4);
            half8_t af;
            af[0] = (_Float16)xa.x; af[1] = (_Float16)xa.y;
            af[2] = (_Float16)xa.z; af[3] = (_Float16)xa.w;
            af[4] = (_Float16)xb.x; af[5] = (_Float16)xb.y;
            af[6] = (_Float16)xb.z; af[7] = (_Float16)xb.w;
            #pragma unroll
            for (int ct = 0; ct < 4; ++ct)
                acc[ct] = __builtin_amdgcn_mfma_f32_16x16x32_f16(
                    af, bfrag[ks][ct], acc[ct], 0, 0, 0);
        }

        #pragma unroll
        for (int reg = 0; reg < 4; ++reg) {
            const int row = rowbase + quad * 4 + reg;
            const bool valid = row < n;

            float4 ps, pd;
            ps.x = acc[0][reg] * avs[0]; pd.x = acc[0][reg] * avd[0];
            ps.y = acc[1][reg] * avs[1]; pd.y = acc[1][reg] * avd[1];
            ps.z = acc[2][reg] * avs[2]; pd.z = acc[2][reg] * avd[2];
            ps.w = acc[3][reg] * avs[3]; pd.w = acc[3][reg] * avd[3];
            #pragma unroll
            for (int off = 8; off >= 1; off >>= 1) {
                ps.x += __shfl_xor(ps.x, off, 64); pd.x += __shfl_xor(pd.x, off, 64);
                ps.y += __shfl_xor(ps.y, off, 64); pd.y += __shfl_xor(pd.y, off, 64);
                ps.z += __shfl_xor(ps.z, off, 64); pd.z += __shfl_xor(pd.z, off, 64);
                ps.w += __shfl_xor(ps.w, off, 64); pd.w += __shfl_xor(pd.w, off, 64);
            }
            if (valid) {
                #pragma unroll
                for (int ct = 0; ct < 4; ++ct)
                    h1[(size_t)row * HC + ct * 16 + l16] =
                        __float2half_rn(acc[ct][reg]);
                if (l16 == 0) {
                    *(float4*)(as1 + (size_t)row * HEADS) = ps;
                    *(float4*)(ad1 + (size_t)row * HEADS) = pd;
                }
            }
        }
    }
}

// ---------------------------------------------------------------------------
// CSR build (locality-preserving, no global atomics, no memset)
// ---------------------------------------------------------------------------
__global__ __launch_bounds__(256) void k_hist(
    const int* __restrict__ edst, int* __restrict__ hist, int E, int nbk)
{
    __shared__ int lh[256];
    const int w = blockIdx.x, t = threadIdx.x;
    for (int i = t; i < nbk; i += 256) lh[i] = 0;
    __syncthreads();
    const int lo = w * CHUNK, hi = min(E, lo + CHUNK);
    for (int e = lo + t; e < hi; e += 256)
        atomicAdd(&lh[edst[e] >> BK_SH], 1);
    __syncthreads();
    for (int i = t; i < nbk; i += 256) hist[(size_t)w * nbk + i] = lh[i];
}

__global__ __launch_bounds__(256) void k_colscan(
    int* __restrict__ hist, int* __restrict__ colsum, int nbk, int nw)
{
    __shared__ int wred[4];
    const int b = blockIdx.x, t = threadIdx.x;
    const int lane = t & 63, w = t >> 6;
    const int v = (t < nw) ? hist[(size_t)t * nbk + b] : 0;
    int sc = v;
    #pragma unroll
    for (int off = 1; off < 64; off <<= 1) {
        int u = __shfl_up(sc, off, 64);
        if (lane >= off) sc += u;
    }
    if (lane == 63) wred[w] = sc;
    __syncthreads();
    if (t == 0) { int a = 0; for (int i = 0; i < 4; ++i) { int xx = wred[i]; wred[i] = a; a += xx; } }
    __syncthreads();
    const int excl = sc - v + wred[w];
    if (t < nw) hist[(size_t)t * nbk + b] = excl;
    if (t == nw - 1) colsum[b] = excl + v;
}

__global__ __launch_bounds__(256) void k_bscan(
    const int* __restrict__ colsum, int* __restrict__ bstart, int nbk, int E)
{
    __shared__ int wred[4];
    const int t = threadIdx.x, lane = t & 63, w = t >> 6;
    const int v = (t < nbk) ? colsum[t] : 0;
    int sc = v;
    #pragma unroll
    for (int off = 1; off < 64; off <<= 1) {
        int u = __shfl_up(sc, off, 64);
        if (lane >= off) sc += u;
    }
    if (lane == 63) wred[w] = sc;
    __syncthreads();
    if (t == 0) { int a = 0; for (int i = 0; i < 4; ++i) { int xx = wred[i]; wred[i] = a; a += xx; } }
    __syncthreads();
    if (t < nbk) bstart[t] = sc - v + wred[w];
    if (t == 0) bstart[nbk] = E;
}

__global__ __launch_bounds__(256) void k_scatter(
    const int* __restrict__ esrc, const int* __restrict__ edst,
    const int* __restrict__ hist, const int* __restrict__ bstart,
    int2* __restrict__ pairs, int E, int nbk)
{
    __shared__ int cur[256];
    const int w = blockIdx.x, t = threadIdx.x;
    for (int i = t; i < nbk; i += 256)
        cur[i] = bstart[i] + hist[(size_t)w * nbk + i];
    __syncthreads();
    const int lo = w * CHUNK, hi = min(E, lo + CHUNK);
    for (int e = lo + t; e < hi; e += 256) {
        const int s = esrc[e], d = edst[e];
        const int pos = atomicAdd(&cur[d >> BK_SH], 1);
        pairs[pos] = make_int2(s, d);
    }
}

__global__ __launch_bounds__(256) void k_build(
    const int2* __restrict__ pairs, const int* __restrict__ bstart,
    int* __restrict__ rowptr, int* __restrict__ csr, int n, int nbk)
{
    __shared__ int cnt[512];
    __shared__ int cur[512];
    __shared__ int stage[STAGE];
    __shared__ int wred[4];
    const int b = blockIdx.x, t = threadIdx.x;
    const int base = bstart[b], eend = bstart[b + 1], m = eend - base;
    const int n0 = b << BK_SH;
    const int nn = min(512, n - n0);

    cnt[t] = 0; cnt[t + 256] = 0;
    __syncthreads();
    for (int e = base + t; e < eend; e += 256)
        atomicAdd(&cnt[pairs[e].y - n0], 1);
    __syncthreads();

    const int c0 = cnt[2 * t], c1 = cnt[2 * t + 1];
    const int s = c0 + c1;
    const int lane = t & 63, w = t >> 6;
    int sc = s;
    #pragma unroll
    for (int off = 1; off < 64; off <<= 1) {
        int u = __shfl_up(sc, off, 64);
        if (lane >= off) sc += u;
    }
    if (lane == 63) wred[w] = sc;
    __syncthreads();
    if (t == 0) { int a = 0; for (int i = 0; i < 4; ++i) { int xx = wred[i]; wred[i] = a; a += xx; } }
    __syncthreads();
    const int excl = sc - s + wred[w];
    cur[2 * t]     = excl;
    cur[2 * t + 1] = excl + c0;
    if (2 * t < nn)     rowptr[n0 + 2 * t]     = base + excl + c0;
    if (2 * t + 1 < nn) rowptr[n0 + 2 * t + 1] = base + excl + c0 + c1;
    __syncthreads();

    for (int e = base + t; e < eend; e += 256) {
        const int2 p = pairs[e];
        const int loc = atomicAdd(&cur[p.y - n0], 1);
        if (loc < STAGE) stage[loc] = p.x;
        else             csr[base + loc] = p.x;
    }
    __syncthreads();
    const int lim = min(m, STAGE);
    for (int i = t; i < lim; i += 256) csr[base + i] = stage[i];
}

// ---------------------------------------------------------------------------
// Degree-sorted node permutation: 128-bin histogram -> scan -> fill.
// ---------------------------------------------------------------------------
__global__ __launch_bounds__(256) void k_dhist(
    const int* __restrict__ rowptr, int* __restrict__ dhist, int n)
{
    __shared__ int lh[128];
    if (threadIdx.x < 128) lh[threadIdx.x] = 0;
    __syncthreads();
    for (int i = blockIdx.x * 256 + threadIdx.x; i < n; i += gridDim.x * 256) {
        const int d = min(rowptr[i] - (i ? rowptr[i - 1] : 0), 127);
        atomicAdd(&lh[d], 1);
    }
    __syncthreads();
    if (threadIdx.x < 128 && lh[threadIdx.x])
        atomicAdd(&dhist[threadIdx.x], lh[threadIdx.x]);
}

__global__ __launch_bounds__(128) void k_dscan(
    const int* __restrict__ dhist, int* __restrict__ dcur)
{
    __shared__ int ws2[2];
    const int t = threadIdx.x, lane = t & 63, w = t >> 6;
    const int v = dhist[t];
    int sc = v;
    #pragma unroll
    for (int off = 1; off < 64; off <<= 1) {
        int u = __shfl_up(sc, off, 64);
        if (lane >= off) sc += u;
    }
    if (lane == 63) ws2[w] = sc;
    __syncthreads();
    dcur[t] = sc - v + ((w == 1) ? ws2[0] : 0);
}

__global__ __launch_bounds__(256) void k_dfill(
    const int* __restrict__ rowptr, int* __restrict__ dcur,
    int* __restrict__ perm, int n)
{
    for (int i = blockIdx.x * 256 + threadIdx.x; i < n; i += gridDim.x * 256) {
        const int d = min(rowptr[i] - (i ? rowptr[i - 1] : 0), 127);
        const int pos = atomicAdd(&dcur[d], 1);
        perm[pos] = i;
    }
}

// ---------------------------------------------------------------------------
// Kernel agg1: one 16-lane group per node, degree-sorted order (perm).
// fp16 W2 in LDS (occupancy), software-pipelined gather loop.
// ---------------------------------------------------------------------------
__global__ __launch_bounds__(256) void k_agg1(
    const int* __restrict__ csr, const int* __restrict__ rowptr,
    const int* __restrict__ perm,
    const __half* __restrict__ h1, const float* __restrict__ as1,
    const float* __restrict__ ad1,
    const float* __restrict__ bias1, const float* __restrict__ gamma,
    const float* __restrict__ beta, const float* __restrict__ mean,
    const float* __restrict__ var,
    const float* __restrict__ W2, const float* __restrict__ ats2,
    const float* __restrict__ atd2,
    __half* __restrict__ g, float* __restrict__ as2o, float* __restrict__ ad2o,
    int n)
{
    __shared__ _Float16 sWh[NCLASS * HC];  // 5 KB, [k][c]
    __shared__ float sh[16][68];           // 4.25 KB
    __shared__ float sE[16][132];          // 8.25 KB
    __shared__ int   sS[16][33];           // 2.06 KB
    for (int i = threadIdx.x; i < NCLASS * HC; i += 256) sWh[i] = (_Float16)W2[i];
    __syncthreads();

    const int gi = threadIdx.x >> 4;
    const int q  = threadIdx.x & 15;
    const int myh = q >> 2;

    const float4 b1v = *(const float4*)(bias1 + 4 * q);
    const float4 gmv = *(const float4*)(gamma + 4 * q);
    const float4 vrv = *(const float4*)(var   + 4 * q);
    const float4 mnv = *(const float4*)(mean  + 4 * q);
    const float4 btv = *(const float4*)(beta  + 4 * q);
    float4 scv, shv;
    scv.x = gmv.x * rsqrtf(vrv.x + BN_EPS);
    scv.y = gmv.y * rsqrtf(vrv.y + BN_EPS);
    scv.z = gmv.z * rsqrtf(vrv.z + BN_EPS);
    scv.w = gmv.w * rsqrtf(vrv.w + BN_EPS);
    shv.x = btv.x - mnv.x * scv.x;
    shv.y = btv.y - mnv.y * scv.y;
    shv.z = btv.z - mnv.z * scv.z;
    shv.w = btv.w - mnv.w * scv.w;
    float4 at2 = {0.f, 0.f, 0.f, 0.f}, dt2 = {0.f, 0.f, 0.f, 0.f};
    if (q < 10) {
        at2 = *(const float4*)(ats2 + 4 * q);
        dt2 = *(const float4*)(atd2 + 4 * q);
    }

    for (int node0 = blockIdx.x * 16; node0 < n; node0 += gridDim.x * 16) {
        const int idx = node0 + gi;
        if (idx >= n) continue;
        const int node = perm[idx];

        const float4 adv = *(const float4*)(ad1 + node * HEADS);
        const float4 sv4 = *(const float4*)(as1 + node * HEADS);
        float4 eself;
        eself.x = __expf(leaky(sv4.x + adv.x));
        eself.y = __expf(leaky(sv4.y + adv.y));
        eself.z = __expf(leaky(sv4.z + adv.z));
        eself.w = __expf(leaky(sv4.w + adv.w));
        const float es = (myh == 0) ? eself.x : (myh == 1) ? eself.y
                       : (myh == 2) ? eself.z : eself.w;

        float2 raws = *(const float2*)(h1 + (size_t)node * HC + 4 * q);
        const float2 s0v = __half22float2(*(__half2*)&raws.x);
        const float2 s1v = __half22float2(*(__half2*)&raws.y);
        float4 acc;
        acc.x = es * s0v.x; acc.y = es * s0v.y;
        acc.z = es * s1v.x; acc.w = es * s1v.y;
        float4 dpart = {0.f, 0.f, 0.f, 0.f};

        const int start = (node == 0) ? 0 : rowptr[node - 1];
        const int end   = rowptr[node];

        for (int base = start; base < end; base += 32) {
            const int m = min(32, end - base);
            float4 ea = {0.f, 0.f, 0.f, 0.f}, eb = {0.f, 0.f, 0.f, 0.f};
            int ia = 0, ib = 0;
            if (q < m) {
                ia = csr[base + q];
                const float4 s4 = *(const float4*)(as1 + (size_t)ia * HEADS);
                ea.x = __expf(leaky(s4.x + adv.x));
                ea.y = __expf(leaky(s4.y + adv.y));
                ea.z = __expf(leaky(s4.z + adv.z));
                ea.w = __expf(leaky(s4.w + adv.w));
            }
            if (q + 16 < m) {
                ib = csr[base + q + 16];
                const float4 s4 = *(const float4*)(as1 + (size_t)ib * HEADS);
                eb.x = __expf(leaky(s4.x + adv.x));
                eb.y = __expf(leaky(s4.y + adv.y));
                eb.z = __expf(leaky(s4.z + adv.z));
                eb.w = __expf(leaky(s4.w + adv.w));
            }
            dpart.x += ea.x + eb.x; dpart.y += ea.y + eb.y;
            dpart.z += ea.z + eb.z; dpart.w += ea.w + eb.w;
            *(float4*)&sE[gi][4 * q] = ea;
            *(float4*)&sE[gi][4 * (q + 16)] = eb;
            sS[gi][q] = ia; sS[gi][q + 16] = ib;
            __threadfence_block();

            const int*   sB = &sS[gi][0];
            const float* eB = &sE[gi][0];
            // software-pipelined: 2 gather rows in flight
            int j = 0;
            const int sa0 = sB[0];
            const int sa1 = sB[(m > 1) ? 1 : 0];
            float2 w0 = *(const float2*)(h1 + (size_t)sa0 * HC + 4 * q);
            float2 w1 = *(const float2*)(h1 + (size_t)sa1 * HC + 4 * q);
            for (; j + 2 < m; j += 2) {
                const int sn0 = sB[j + 2];
                const int sn1 = sB[(j + 3 < m) ? (j + 3) : (j + 2)];
                const float2 v0 = *(const float2*)(h1 + (size_t)sn0 * HC + 4 * q);
                const float2 v1 = *(const float2*)(h1 + (size_t)sn1 * HC + 4 * q);
                const float e0 = eB[(j + 0) * 4 + myh];
                const float e1 = eB[(j + 1) * 4 + myh];
                const float2 a0 = __half22float2(*(const __half2*)&w0.x);
                const float2 a1 = __half22float2(*(const __half2*)&w0.y);
                const float2 b0 = __half22float2(*(const __half2*)&w1.x);
                const float2 b1 = __half22float2(*(const __half2*)&w1.y);
                acc.x = fmaf(e0, a0.x, acc.x); acc.y = fmaf(e0, a0.y, acc.y);
                acc.z = fmaf(e0, a1.x, acc.z); acc.w = fmaf(e0, a1.y, acc.w);
                acc.x = fmaf(e1, b0.x, acc.x); acc.y = fmaf(e1, b0.y, acc.y);
                acc.z = fmaf(e1, b1.x, acc.z); acc.w = fmaf(e1, b1.y, acc.w);
                w0 = v0; w1 = v1;
            }
            {
                const float e0 = eB[j * 4 + myh];
                const float e1 = (j + 1 < m) ? eB[(j + 1) * 4 + myh] : 0.f;
                const float2 a0 = __half22float2(*(const __half2*)&w0.x);
                const float2 a1 = __half22float2(*(const __half2*)&w0.y);
                const float2 b0 = __half22float2(*(const __half2*)&w1.x);
                const float2 b1 = __half22float2(*(const __half2*)&w1.y);
                acc.x = fmaf(e0, a0.x, acc.x); acc.y = fmaf(e0, a0.y, acc.y);
                acc.z = fmaf(e0, a1.x, acc.z); acc.w = fmaf(e0, a1.y, acc.w);
                acc.x = fmaf(e1, b0.x, acc.x); acc.y = fmaf(e1, b0.y, acc.y);
                acc.z = fmaf(e1, b1.x, acc.z); acc.w = fmaf(e1, b1.y, acc.w);
            }
            __threadfence_block();
        }

        #pragma unroll
        for (int off = 8; off >= 1; off >>= 1) {
            dpart.x += __shfl_xor(dpart.x, off, 64);
            dpart.y += __shfl_xor(dpart.y, off, 64);
            dpart.z += __shfl_xor(dpart.z, off, 64);
            dpart.w += __shfl_xor(dpart.w, off, 64);
        }
        const float den = es + ((myh == 0) ? dpart.x : (myh == 1) ? dpart.y
                               : (myh == 2) ? dpart.z : dpart.w);
        const float rden = 1.f / den;

        float4 v;
        v.x = fmaxf(fmaf(acc.x * rden + b1v.x, scv.x, shv.x), 0.f);
        v.y = fmaxf(fmaf(acc.y * rden + b1v.y, scv.y, shv.y), 0.f);
        v.z = fmaxf(fmaf(acc.z * rden + b1v.z, scv.z, shv.z), 0.f);
        v.w = fmaxf(fmaf(acc.w * rden + b1v.w, scv.w, shv.w), 0.f);
        *(float4*)&sh[gi][4 * q] = v;
        __threadfence_block();

        float4 gacc = {0.f, 0.f, 0.f, 0.f};
        if (q < 10) {
            #pragma unroll 8
            for (int k = 0; k < HC; ++k) {
                const float hk = sh[gi][k];
                const half4_t wv = *(const half4_t*)&sWh[k * NCLASS + 4 * q];
                gacc.x = fmaf(hk, (float)wv[0], gacc.x);
                gacc.y = fmaf(hk, (float)wv[1], gacc.y);
                gacc.z = fmaf(hk, (float)wv[2], gacc.z);
                gacc.w = fmaf(hk, (float)wv[3], gacc.w);
            }
        }
        __half2 p0 = __float22half2_rn({gacc.x, gacc.y});
        __half2 p1 = __float22half2_rn({gacc.z, gacc.w});
        float2 packed; *(__half2*)&packed.x = p0; *(__half2*)&packed.y = p1;
        *(float2*)(g + (size_t)node * HC + 4 * q) = packed;

        float sv = gacc.x * at2.x + gacc.y * at2.y + gacc.z * at2.z + gacc.w * at2.w;
        float dv = gacc.x * dt2.x + gacc.y * dt2.y + gacc.z * dt2.z + gacc.w * dt2.w;
        #pragma unroll
        for (int off = 8; off >= 1; off >>= 1) {
            sv += __shfl_xor(sv, off, 64);
            dv += __shfl_xor(dv, off, 64);
        }
        if (q == 0) { as2o[node] = sv; ad2o[node] = dv; }
        __threadfence_block();
    }
}

// ---------------------------------------------------------------------------
// Kernel agg2: one 16-lane group per node (degree-sorted), pipelined gathers.
// ---------------------------------------------------------------------------
__global__ __launch_bounds__(256) void k_agg2(
    const int* __restrict__ csr, const int* __restrict__ rowptr,
    const int* __restrict__ perm,
    const __half* __restrict__ g, const float* __restrict__ as2,
    const float* __restrict__ ad2, const float* __restrict__ bias2,
    float* __restrict__ out, int n)
{
    __shared__ float sE[16][34];
    __shared__ int   sS[16][33];
    const int gi = threadIdx.x >> 4;
    const int q  = threadIdx.x & 15;

    float4 b2v = {0.f, 0.f, 0.f, 0.f};
    if (q < 10) b2v = *(const float4*)(bias2 + 4 * q);

    for (int node0 = blockIdx.x * 16; node0 < n; node0 += gridDim.x * 16) {
        const int idx = node0 + gi;
        if (idx >= n) continue;
        const int node = perm[idx];

        const float ad2d = ad2[node];
        const float eself = __expf(leaky(as2[node] + ad2d));

        float2 raws = *(const float2*)(g + (size_t)node * HC + 4 * q);
        const float2 s0v = __half22float2(*(__half2*)&raws.x);
        const float2 s1v = __half22float2(*(__half2*)&raws.y);
        float4 acc;
        acc.x = eself * s0v.x; acc.y = eself * s0v.y;
        acc.z = eself * s1v.x; acc.w = eself * s1v.y;
        float dpart = 0.f;

        const int start = (node == 0) ? 0 : rowptr[node - 1];
        const int end   = rowptr[node];

        for (int base = start; base < end; base += 32) {
            const int m = min(32, end - base);
            float ea = 0.f, eb = 0.f;
            int ia = 0, ib = 0;
            if (q < m) {
                ia = csr[base + q];
                ea = __expf(leaky(as2[ia] + ad2d));
            }
            if (q + 16 < m) {
                ib = csr[base + q + 16];
                eb = __expf(leaky(as2[ib] + ad2d));
            }
            dpart += ea + eb;
            sE[gi][q] = ea; sE[gi][q + 16] = eb;
            sS[gi][q] = ia; sS[gi][q + 16] = ib;
            __threadfence_block();

            const int*   sB = &sS[gi][0];
            const float* eB = &sE[gi][0];
            int j = 0;
            const int sa0 = sB[0];
            const int sa1 = sB[(m > 1) ? 1 : 0];
            float2 w0 = *(const float2*)(g + (size_t)sa0 * HC + 4 * q);
            float2 w1 = *(const float2*)(g + (size_t)sa1 * HC + 4 * q);
            for (; j + 2 < m; j += 2) {
                const int sn0 = sB[j + 2];
                const int sn1 = sB[(j + 3 < m) ? (j + 3) : (j + 2)];
                const float2 v0 = *(const float2*)(g + (size_t)sn0 * HC + 4 * q);
                const float2 v1 = *(const float2*)(g + (size_t)sn1 * HC + 4 * q);
                const float e0 = eB[j + 0];
                const float e1 = eB[j + 1];
                const float2 a0 = __half22float2(*(const __half2*)&w0.x);
                const float2 a1 = __half22float2(*(const __half2*)&w0.y);
                const float2 b0 = __half22float2(*(const __half2*)&w1.x);
                const float2 b1 = __half22float2(*(const __half2*)&w1.y);
                acc.x = fmaf(e0, a0.x, acc.x); acc.y = fmaf(e0, a0.y, acc.y);
                acc.z = fmaf(e0, a1.x, acc.z); acc.w = fmaf(e0, a1.y, acc.w);
                acc.x = fmaf(e1, b0.x, acc.x); acc.y = fmaf(e1, b0.y, acc.y);
                acc.z = fmaf(e1, b1.x, acc.z); acc.w = fmaf(e1, b1.y, acc.w);
                w0 = v0; w1 = v1;
            }
            {
                const float e0 = eB[j];
                const float e1 = (j + 1 < m) ? eB[j + 1] : 0.f;
                const float2 a0 = __half22float2(*(const __half2*)&w0.x);
                const float2 a1 = __half22float2(*(const __half2*)&w0.y);
                const float2 b0 = __half22float2(*(const __half2*)&w1.x);
                const float2 b1 = __half22float2(*(const __half2*)&w1.y);
                acc.x = fmaf(e0, a0.x, acc.x); acc.y = fmaf(e0, a0.y, acc.y);
                acc.z = fmaf(e0, a1.x, acc.z); acc.w = fmaf(e0, a1.y, acc.w);
                acc.x = fmaf(e1, b0.x, acc.x); acc.y = fmaf(e1, b0.y, acc.y);
                acc.z = fmaf(e1, b1.x, acc.z); acc.w = fmaf(e1, b1.y, acc.w);
            }
            __threadfence_block();
        }

        #pragma unroll
        for (int off = 8; off >= 1; off >>= 1)
            dpart += __shfl_xor(dpart, off, 64);
        const float rden = 1.f / (dpart + eself);

        if (q < 10) {
            float4 r;
            r.x = acc.x * rden + b2v.x;
            r.y = acc.y * rden + b2v.y;
            r.z = acc.z * rden + b2v.z;
            r.w = acc.w * rden + b2v.w;
            *(float4*)(out + (size_t)node * NCLASS + 4 * q) = r;
        }
    }
}

extern "C" void kernel_launch(void* const* d_in, const int* in_sizes, int n_in,
                              void* d_out, int out_size, void* d_ws, size_t ws_size,
                              hipStream_t stream)
{
    const float* x    = (const float*)d_in[0];
    const int*   ei   = (const int*)  d_in[1];
    const float* W1   = (const float*)d_in[2];
    const float* as1w = (const float*)d_in[3];
    const float* ad1w = (const float*)d_in[4];
    const float* b1   = (const float*)d_in[5];
    const float* gm   = (const float*)d_in[6];
    const float* bt   = (const float*)d_in[7];
    const float* mn   = (const float*)d_in[8];
    const float* vr   = (const float*)d_in[9];
    const float* W2   = (const float*)d_in[10];
    const float* as2w = (const float*)d_in[11];
    const float* ad2w = (const float*)d_in[12];
    const float* b2   = (const float*)d_in[13];

    const int n = in_sizes[0] / NFEAT;           // 100000
    const int E = in_sizes[1] / 2;               // 1600000
    const int* esrc = ei;
    const int* edst = ei + E;

    const int nbk = (n + 511) >> BK_SH;          // 196 buckets
    const int nw  = (E + CHUNK - 1) / CHUNK;     // 196 chunks

    float*  ws   = (float*)d_ws;
    __half* h1   = (__half*)ws;
    float*  a_s1 = ws   + (size_t)n * 32;
    float*  a_d1 = a_s1 + (size_t)n * 4;
    __half* gbuf = (__half*)(a_d1 + (size_t)n * 4);
    float*  a_s2 = a_d1 + (size_t)n * 4 + (size_t)n * 32;
    float*  a_d2 = a_s2 + n;
    int2*   pairs  = (int2*)(a_d2 + n);
    int*    csr    = (int*)(pairs + E);
    int*    rowptr = csr + E;
    int*    hist   = rowptr + n;
    int*    colsum = hist + (size_t)nw * nbk;
    int*    bstart = colsum + nbk;
    int*    perm   = bstart + (nbk + 1);
    int*    dhist  = perm + n;
    int*    dcur   = dhist + 128;
    float*  outv = (float*)d_out;

    const int nblk = (n + 15) / 16;

    hipMemsetAsync(dhist, 0, 256 * sizeof(int), stream);   // dhist + dcur

    k_hist   <<<nw, 256, 0, stream>>>(edst, hist, E, nbk);
    k_colscan<<<nbk, 256, 0, stream>>>(hist, colsum, nbk, nw);
    k_bscan  <<<1, 256, 0, stream>>>(colsum, bstart, nbk, E);
    k_scatter<<<nw, 256, 0, stream>>>(esrc, edst, hist, bstart, pairs, E, nbk);
    k_build  <<<nbk, 256, 0, stream>>>(pairs, bstart, rowptr, csr, n, nbk);
    k_dhist  <<<256, 256, 0, stream>>>(rowptr, dhist, n);
    k_dscan  <<<1, 128, 0, stream>>>(dhist, dcur);
    k_dfill  <<<256, 256, 0, stream>>>(rowptr, dcur, perm, n);
    k_gemm1  <<<512, 256, 0, stream>>>(x, W1, as1w, ad1w, h1, a_s1, a_d1, n);
    k_agg1   <<<nblk, 256, 0, stream>>>(csr, rowptr, perm, h1, a_s1, a_d1,
                                        b1, gm, bt, mn, vr,
                                        W2, as2w, ad2w, gbuf, a_s2, a_d2, n);
    k_agg2   <<<nblk, 256, 0, stream>>>(csr, rowptr, perm, gbuf, a_s2, a_d2,
                                        b2, outv, n);
}

// Round 9
// 293.992 us; speedup vs baseline: 2.0208x; 2.0208x over previous
//
#include <hip/hip_runtime.h>
#include <hip/hip_bf16.h>
#include <hip/hip_fp16.h>

#define NFEAT  128
#define HC     64
#define HEADS  4
#define NHID   16
#define NCLASS 40
#define NEG    0.2f
#define BN_EPS 1e-5f

#define BK_SH   9          // 512 nodes per bucket
#define CHUNK   8192       // edges per histogram/scatter workgroup
#define STAGE   12288      // LDS staging capacity in k_build

typedef _Float16 half8_t __attribute__((ext_vector_type(8)));
typedef _Float16 half4_t __attribute__((ext_vector_type(4)));
typedef float    f32x4_t __attribute__((ext_vector_type(4)));

__device__ __forceinline__ float leaky(float a) { return (a > 0.f) ? a : NEG * a; }

// ---------------------------------------------------------------------------
// Kernel 1 (MFMA): h1 = x @ W1 via v_mfma_f32_16x16x32_f16.
// ---------------------------------------------------------------------------
__global__ __launch_bounds__(256) void k_gemm1(
    const float* __restrict__ x, const float* __restrict__ W1,
    const float* __restrict__ att_s, const float* __restrict__ att_d,
    __half* __restrict__ h1, float* __restrict__ as1, float* __restrict__ ad1,
    int n)
{
    const int wave = threadIdx.x >> 6, lane = threadIdx.x & 63;
    const int quad = lane >> 4, l16 = lane & 15;

    half8_t bfrag[4][4];
    #pragma unroll
    for (int ks = 0; ks < 4; ++ks)
        #pragma unroll
        for (int ct = 0; ct < 4; ++ct)
            #pragma unroll
            for (int j = 0; j < 8; ++j)
                bfrag[ks][ct][j] =
                    (_Float16)W1[(ks * 32 + quad * 8 + j) * HC + ct * 16 + l16];

    float avs[4], avd[4];
    #pragma unroll
    for (int ct = 0; ct < 4; ++ct) {
        avs[ct] = att_s[ct * 16 + l16];
        avd[ct] = att_d[ct * 16 + l16];
    }

    const int nslab = (n + 15) >> 4;
    for (int slab = blockIdx.x * 4 + wave; slab < nslab; slab += gridDim.x * 4) {
        const int rowbase = slab * 16;
        const int arow = min(rowbase + l16, n - 1);
        const float* xp = x + (size_t)arow * NFEAT;

        f32x4_t acc[4] = {{0.f,0.f,0.f,0.f},{0.f,0.f,0.f,0.f},
                          {0.f,0.f,0.f,0.f},{0.f,0.f,0.f,0.f}};
        #pragma unroll
        for (int ks = 0; ks < 4; ++ks) {
            const float4 xa = *(const float4*)(xp + ks * 32 + quad * 8);
            const float4 xb = *(const float4*)(xp + ks * 32 + quad * 8 + 4);
            half8_t af;
            af[0] = (_Float16)xa.x; af[1] = (_Float16)xa.y;
            af[2] = (_Float16)xa.z; af[3] = (_Float16)xa.w;
            af[4] = (_Float16)xb.x; af[5] = (_Float16)xb.y;
            af[6] = (_Float16)xb.z; af[7] = (_Float16)xb.w;
            #pragma unroll
            for (int ct = 0; ct < 4; ++ct)
                acc[ct] = __builtin_amdgcn_mfma_f32_16x16x32_f16(
                    af, bfrag[ks][ct], acc[ct], 0, 0, 0);
        }

        #pragma unroll
        for (int reg = 0; reg < 4; ++reg) {
            const int row = rowbase + quad * 4 + reg;
            const bool valid = row < n;

            float4 ps, pd;
            ps.x = acc[0][reg] * avs[0]; pd.x = acc[0][reg] * avd[0];
            ps.y = acc[1][reg] * avs[1]; pd.y = acc[1][reg] * avd[1];
            ps.z = acc[2][reg] * avs[2]; pd.z = acc[2][reg] * avd[2];
            ps.w = acc[3][reg] * avs[3]; pd.w = acc[3][reg] * avd[3];
            #pragma unroll
            for (int off = 8; off >= 1; off >>= 1) {
                ps.x += __shfl_xor(ps.x, off, 64); pd.x += __shfl_xor(pd.x, off, 64);
                ps.y += __shfl_xor(ps.y, off, 64); pd.y += __shfl_xor(pd.y, off, 64);
                ps.z += __shfl_xor(ps.z, off, 64); pd.z += __shfl_xor(pd.z, off, 64);
                ps.w += __shfl_xor(ps.w, off, 64); pd.w += __shfl_xor(pd.w, off, 64);
            }
            if (valid) {
                #pragma unroll
                for (int ct = 0; ct < 4; ++ct)
                    h1[(size_t)row * HC + ct * 16 + l16] =
                        __float2half_rn(acc[ct][reg]);
                if (l16 == 0) {
                    *(float4*)(as1 + (size_t)row * HEADS) = ps;
                    *(float4*)(ad1 + (size_t)row * HEADS) = pd;
                }
            }
        }
    }
}

// ---------------------------------------------------------------------------
// CSR build (locality-preserving, no global atomics, no memset)
// ---------------------------------------------------------------------------
__global__ __launch_bounds__(256) void k_hist(
    const int* __restrict__ edst, int* __restrict__ hist, int E, int nbk)
{
    __shared__ int lh[256];
    const int w = blockIdx.x, t = threadIdx.x;
    for (int i = t; i < nbk; i += 256) lh[i] = 0;
    __syncthreads();
    const int lo = w * CHUNK, hi = min(E, lo + CHUNK);
    for (int e = lo + t; e < hi; e += 256)
        atomicAdd(&lh[edst[e] >> BK_SH], 1);
    __syncthreads();
    for (int i = t; i < nbk; i += 256) hist[(size_t)w * nbk + i] = lh[i];
}

__global__ __launch_bounds__(256) void k_colscan(
    int* __restrict__ hist, int* __restrict__ colsum, int nbk, int nw)
{
    __shared__ int wred[4];
    const int b = blockIdx.x, t = threadIdx.x;
    const int lane = t & 63, w = t >> 6;
    const int v = (t < nw) ? hist[(size_t)t * nbk + b] : 0;
    int sc = v;
    #pragma unroll
    for (int off = 1; off < 64; off <<= 1) {
        int u = __shfl_up(sc, off, 64);
        if (lane >= off) sc += u;
    }
    if (lane == 63) wred[w] = sc;
    __syncthreads();
    if (t == 0) { int a = 0; for (int i = 0; i < 4; ++i) { int xx = wred[i]; wred[i] = a; a += xx; } }
    __syncthreads();
    const int excl = sc - v + wred[w];
    if (t < nw) hist[(size_t)t * nbk + b] = excl;
    if (t == nw - 1) colsum[b] = excl + v;
}

__global__ __launch_bounds__(256) void k_bscan(
    const int* __restrict__ colsum, int* __restrict__ bstart, int nbk, int E)
{
    __shared__ int wred[4];
    const int t = threadIdx.x, lane = t & 63, w = t >> 6;
    const int v = (t < nbk) ? colsum[t] : 0;
    int sc = v;
    #pragma unroll
    for (int off = 1; off < 64; off <<= 1) {
        int u = __shfl_up(sc, off, 64);
        if (lane >= off) sc += u;
    }
    if (lane == 63) wred[w] = sc;
    __syncthreads();
    if (t == 0) { int a = 0; for (int i = 0; i < 4; ++i) { int xx = wred[i]; wred[i] = a; a += xx; } }
    __syncthreads();
    if (t < nbk) bstart[t] = sc - v + wred[w];
    if (t == 0) bstart[nbk] = E;
}

__global__ __launch_bounds__(256) void k_scatter(
    const int* __restrict__ esrc, const int* __restrict__ edst,
    const int* __restrict__ hist, const int* __restrict__ bstart,
    int2* __restrict__ pairs, int E, int nbk)
{
    __shared__ int cur[256];
    const int w = blockIdx.x, t = threadIdx.x;
    for (int i = t; i < nbk; i += 256)
        cur[i] = bstart[i] + hist[(size_t)w * nbk + i];
    __syncthreads();
    const int lo = w * CHUNK, hi = min(E, lo + CHUNK);
    for (int e = lo + t; e < hi; e += 256) {
        const int s = esrc[e], d = edst[e];
        const int pos = atomicAdd(&cur[d >> BK_SH], 1);
        pairs[pos] = make_int2(s, d);
    }
}

__global__ __launch_bounds__(256) void k_build(
    const int2* __restrict__ pairs, const int* __restrict__ bstart,
    int* __restrict__ rowptr, int* __restrict__ csr, int n, int nbk)
{
    __shared__ int cnt[512];
    __shared__ int cur[512];
    __shared__ int stage[STAGE];
    __shared__ int wred[4];
    const int b = blockIdx.x, t = threadIdx.x;
    const int base = bstart[b], eend = bstart[b + 1], m = eend - base;
    const int n0 = b << BK_SH;
    const int nn = min(512, n - n0);

    cnt[t] = 0; cnt[t + 256] = 0;
    __syncthreads();
    for (int e = base + t; e < eend; e += 256)
        atomicAdd(&cnt[pairs[e].y - n0], 1);
    __syncthreads();

    const int c0 = cnt[2 * t], c1 = cnt[2 * t + 1];
    const int s = c0 + c1;
    const int lane = t & 63, w = t >> 6;
    int sc = s;
    #pragma unroll
    for (int off = 1; off < 64; off <<= 1) {
        int u = __shfl_up(sc, off, 64);
        if (lane >= off) sc += u;
    }
    if (lane == 63) wred[w] = sc;
    __syncthreads();
    if (t == 0) { int a = 0; for (int i = 0; i < 4; ++i) { int xx = wred[i]; wred[i] = a; a += xx; } }
    __syncthreads();
    const int excl = sc - s + wred[w];
    cur[2 * t]     = excl;
    cur[2 * t + 1] = excl + c0;
    if (2 * t < nn)     rowptr[n0 + 2 * t]     = base + excl + c0;
    if (2 * t + 1 < nn) rowptr[n0 + 2 * t + 1] = base + excl + c0 + c1;
    __syncthreads();

    for (int e = base + t; e < eend; e += 256) {
        const int2 p = pairs[e];
        const int loc = atomicAdd(&cur[p.y - n0], 1);
        if (loc < STAGE) stage[loc] = p.x;
        else             csr[base + loc] = p.x;
    }
    __syncthreads();
    const int lim = min(m, STAGE);
    for (int i = t; i < lim; i += 256) csr[base + i] = stage[i];
}

// ---------------------------------------------------------------------------
// Kernel agg1: one 16-lane group per node (identity order).
// fp16 W2 in LDS (occupancy), software-pipelined gather loop.
// ---------------------------------------------------------------------------
__global__ __launch_bounds__(256) void k_agg1(
    const int* __restrict__ csr, const int* __restrict__ rowptr,
    const __half* __restrict__ h1, const float* __restrict__ as1,
    const float* __restrict__ ad1,
    const float* __restrict__ bias1, const float* __restrict__ gamma,
    const float* __restrict__ beta, const float* __restrict__ mean,
    const float* __restrict__ var,
    const float* __restrict__ W2, const float* __restrict__ ats2,
    const float* __restrict__ atd2,
    __half* __restrict__ g, float* __restrict__ as2o, float* __restrict__ ad2o,
    int n)
{
    __shared__ _Float16 sWh[NCLASS * HC];  // 5 KB, [k][c]
    __shared__ float sh[16][68];           // 4.25 KB
    __shared__ float sE[16][132];          // 8.25 KB
    __shared__ int   sS[16][33];           // 2.06 KB
    for (int i = threadIdx.x; i < NCLASS * HC; i += 256) sWh[i] = (_Float16)W2[i];
    __syncthreads();

    const int gi = threadIdx.x >> 4;
    const int q  = threadIdx.x & 15;
    const int myh = q >> 2;

    const float4 b1v = *(const float4*)(bias1 + 4 * q);
    const float4 gmv = *(const float4*)(gamma + 4 * q);
    const float4 vrv = *(const float4*)(var   + 4 * q);
    const float4 mnv = *(const float4*)(mean  + 4 * q);
    const float4 btv = *(const float4*)(beta  + 4 * q);
    float4 scv, shv;
    scv.x = gmv.x * rsqrtf(vrv.x + BN_EPS);
    scv.y = gmv.y * rsqrtf(vrv.y + BN_EPS);
    scv.z = gmv.z * rsqrtf(vrv.z + BN_EPS);
    scv.w = gmv.w * rsqrtf(vrv.w + BN_EPS);
    shv.x = btv.x - mnv.x * scv.x;
    shv.y = btv.y - mnv.y * scv.y;
    shv.z = btv.z - mnv.z * scv.z;
    shv.w = btv.w - mnv.w * scv.w;
    float4 at2 = {0.f, 0.f, 0.f, 0.f}, dt2 = {0.f, 0.f, 0.f, 0.f};
    if (q < 10) {
        at2 = *(const float4*)(ats2 + 4 * q);
        dt2 = *(const float4*)(atd2 + 4 * q);
    }

    for (int node0 = blockIdx.x * 16; node0 < n; node0 += gridDim.x * 16) {
        const int node = node0 + gi;
        if (node >= n) continue;

        const float4 adv = *(const float4*)(ad1 + node * HEADS);
        const float4 sv4 = *(const float4*)(as1 + node * HEADS);
        float4 eself;
        eself.x = __expf(leaky(sv4.x + adv.x));
        eself.y = __expf(leaky(sv4.y + adv.y));
        eself.z = __expf(leaky(sv4.z + adv.z));
        eself.w = __expf(leaky(sv4.w + adv.w));
        const float es = (myh == 0) ? eself.x : (myh == 1) ? eself.y
                       : (myh == 2) ? eself.z : eself.w;

        float2 raws = *(const float2*)(h1 + (size_t)node * HC + 4 * q);
        const float2 s0v = __half22float2(*(__half2*)&raws.x);
        const float2 s1v = __half22float2(*(__half2*)&raws.y);
        float4 acc;
        acc.x = es * s0v.x; acc.y = es * s0v.y;
        acc.z = es * s1v.x; acc.w = es * s1v.y;
        float4 dpart = {0.f, 0.f, 0.f, 0.f};

        const int start = (node == 0) ? 0 : rowptr[node - 1];
        const int end   = rowptr[node];

        for (int base = start; base < end; base += 32) {
            const int m = min(32, end - base);
            float4 ea = {0.f, 0.f, 0.f, 0.f}, eb = {0.f, 0.f, 0.f, 0.f};
            int ia = 0, ib = 0;
            if (q < m) {
                ia = csr[base + q];
                const float4 s4 = *(const float4*)(as1 + (size_t)ia * HEADS);
                ea.x = __expf(leaky(s4.x + adv.x));
                ea.y = __expf(leaky(s4.y + adv.y));
                ea.z = __expf(leaky(s4.z + adv.z));
                ea.w = __expf(leaky(s4.w + adv.w));
            }
            if (q + 16 < m) {
                ib = csr[base + q + 16];
                const float4 s4 = *(const float4*)(as1 + (size_t)ib * HEADS);
                eb.x = __expf(leaky(s4.x + adv.x));
                eb.y = __expf(leaky(s4.y + adv.y));
                eb.z = __expf(leaky(s4.z + adv.z));
                eb.w = __expf(leaky(s4.w + adv.w));
            }
            dpart.x += ea.x + eb.x; dpart.y += ea.y + eb.y;
            dpart.z += ea.z + eb.z; dpart.w += ea.w + eb.w;
            *(float4*)&sE[gi][4 * q] = ea;
            *(float4*)&sE[gi][4 * (q + 16)] = eb;
            sS[gi][q] = ia; sS[gi][q + 16] = ib;
            __threadfence_block();

            const int*   sB = &sS[gi][0];
            const float* eB = &sE[gi][0];
            int j = 0;
            const int sa0 = sB[0];
            const int sa1 = sB[(m > 1) ? 1 : 0];
            float2 w0 = *(const float2*)(h1 + (size_t)sa0 * HC + 4 * q);
            float2 w1 = *(const float2*)(h1 + (size_t)sa1 * HC + 4 * q);
            for (; j + 2 < m; j += 2) {
                const int sn0 = sB[j + 2];
                const int sn1 = sB[(j + 3 < m) ? (j + 3) : (j + 2)];
                const float2 v0 = *(const float2*)(h1 + (size_t)sn0 * HC + 4 * q);
                const float2 v1 = *(const float2*)(h1 + (size_t)sn1 * HC + 4 * q);
                const float e0 = eB[(j + 0) * 4 + myh];
                const float e1 = eB[(j + 1) * 4 + myh];
                const float2 a0 = __half22float2(*(const __half2*)&w0.x);
                const float2 a1 = __half22float2(*(const __half2*)&w0.y);
                const float2 b0 = __half22float2(*(const __half2*)&w1.x);
                const float2 b1 = __half22float2(*(const __half2*)&w1.y);
                acc.x = fmaf(e0, a0.x, acc.x); acc.y = fmaf(e0, a0.y, acc.y);
                acc.z = fmaf(e0, a1.x, acc.z); acc.w = fmaf(e0, a1.y, acc.w);
                acc.x = fmaf(e1, b0.x, acc.x); acc.y = fmaf(e1, b0.y, acc.y);
                acc.z = fmaf(e1, b1.x, acc.z); acc.w = fmaf(e1, b1.y, acc.w);
                w0 = v0; w1 = v1;
            }
            {
                const float e0 = eB[j * 4 + myh];
                const float e1 = (j + 1 < m) ? eB[(j + 1) * 4 + myh] : 0.f;
                const float2 a0 = __half22float2(*(const __half2*)&w0.x);
                const float2 a1 = __half22float2(*(const __half2*)&w0.y);
                const float2 b0 = __half22float2(*(const __half2*)&w1.x);
                const float2 b1 = __half22float2(*(const __half2*)&w1.y);
                acc.x = fmaf(e0, a0.x, acc.x); acc.y = fmaf(e0, a0.y, acc.y);
                acc.z = fmaf(e0, a1.x, acc.z); acc.w = fmaf(e0, a1.y, acc.w);
                acc.x = fmaf(e1, b0.x, acc.x); acc.y = fmaf(e1, b0.y, acc.y);
                acc.z = fmaf(e1, b1.x, acc.z); acc.w = fmaf(e1, b1.y, acc.w);
            }
            __threadfence_block();
        }

        #pragma unroll
        for (int off = 8; off >= 1; off >>= 1) {
            dpart.x += __shfl_xor(dpart.x, off, 64);
            dpart.y += __shfl_xor(dpart.y, off, 64);
            dpart.z += __shfl_xor(dpart.z, off, 64);
            dpart.w += __shfl_xor(dpart.w, off, 64);
        }
        const float den = es + ((myh == 0) ? dpart.x : (myh == 1) ? dpart.y
                               : (myh == 2) ? dpart.z : dpart.w);
        const float rden = 1.f / den;

        float4 v;
        v.x = fmaxf(fmaf(acc.x * rden + b1v.x, scv.x, shv.x), 0.f);
        v.y = fmaxf(fmaf(acc.y * rden + b1v.y, scv.y, shv.y), 0.f);
        v.z = fmaxf(fmaf(acc.z * rden + b1v.z, scv.z, shv.z), 0.f);
        v.w = fmaxf(fmaf(acc.w * rden + b1v.w, scv.w, shv.w), 0.f);
        *(float4*)&sh[gi][4 * q] = v;
        __threadfence_block();

        float4 gacc = {0.f, 0.f, 0.f, 0.f};
        if (q < 10) {
            #pragma unroll 8
            for (int k = 0; k < HC; ++k) {
                const float hk = sh[gi][k];
                const half4_t wv = *(const half4_t*)&sWh[k * NCLASS + 4 * q];
                gacc.x = fmaf(hk, (float)wv[0], gacc.x);
                gacc.y = fmaf(hk, (float)wv[1], gacc.y);
                gacc.z = fmaf(hk, (float)wv[2], gacc.z);
                gacc.w = fmaf(hk, (float)wv[3], gacc.w);
            }
        }
        __half2 p0 = __float22half2_rn({gacc.x, gacc.y});
        __half2 p1 = __float22half2_rn({gacc.z, gacc.w});
        float2 packed; *(__half2*)&packed.x = p0; *(__half2*)&packed.y = p1;
        *(float2*)(g + (size_t)node * HC + 4 * q) = packed;

        float sv = gacc.x * at2.x + gacc.y * at2.y + gacc.z * at2.z + gacc.w * at2.w;
        float dv = gacc.x * dt2.x + gacc.y * dt2.y + gacc.z * dt2.z + gacc.w * dt2.w;
        #pragma unroll
        for (int off = 8; off >= 1; off >>= 1) {
            sv += __shfl_xor(sv, off, 64);
            dv += __shfl_xor(dv, off, 64);
        }
        if (q == 0) { as2o[node] = sv; ad2o[node] = dv; }
        __threadfence_block();
    }
}

// ---------------------------------------------------------------------------
// Kernel agg2: one 16-lane group per node (identity order), pipelined gathers.
// ---------------------------------------------------------------------------
__global__ __launch_bounds__(256) void k_agg2(
    const int* __restrict__ csr, const int* __restrict__ rowptr,
    const __half* __restrict__ g, const float* __restrict__ as2,
    const float* __restrict__ ad2, const float* __restrict__ bias2,
    float* __restrict__ out, int n)
{
    __shared__ float sE[16][34];
    __shared__ int   sS[16][33];
    const int gi = threadIdx.x >> 4;
    const int q  = threadIdx.x & 15;

    float4 b2v = {0.f, 0.f, 0.f, 0.f};
    if (q < 10) b2v = *(const float4*)(bias2 + 4 * q);

    for (int node0 = blockIdx.x * 16; node0 < n; node0 += gridDim.x * 16) {
        const int node = node0 + gi;
        if (node >= n) continue;

        const float ad2d = ad2[node];
        const float eself = __expf(leaky(as2[node] + ad2d));

        float2 raws = *(const float2*)(g + (size_t)node * HC + 4 * q);
        const float2 s0v = __half22float2(*(__half2*)&raws.x);
        const float2 s1v = __half22float2(*(__half2*)&raws.y);
        float4 acc;
        acc.x = eself * s0v.x; acc.y = eself * s0v.y;
        acc.z = eself * s1v.x; acc.w = eself * s1v.y;
        float dpart = 0.f;

        const int start = (node == 0) ? 0 : rowptr[node - 1];
        const int end   = rowptr[node];

        for (int base = start; base < end; base += 32) {
            const int m = min(32, end - base);
            float ea = 0.f, eb = 0.f;
            int ia = 0, ib = 0;
            if (q < m) {
                ia = csr[base + q];
                ea = __expf(leaky(as2[ia] + ad2d));
            }
            if (q + 16 < m) {
                ib = csr[base + q + 16];
                eb = __expf(leaky(as2[ib] + ad2d));
            }
            dpart += ea + eb;
            sE[gi][q] = ea; sE[gi][q + 16] = eb;
            sS[gi][q] = ia; sS[gi][q + 16] = ib;
            __threadfence_block();

            const int*   sB = &sS[gi][0];
            const float* eB = &sE[gi][0];
            int j = 0;
            const int sa0 = sB[0];
            const int sa1 = sB[(m > 1) ? 1 : 0];
            float2 w0 = *(const float2*)(g + (size_t)sa0 * HC + 4 * q);
            float2 w1 = *(const float2*)(g + (size_t)sa1 * HC + 4 * q);
            for (; j + 2 < m; j += 2) {
                const int sn0 = sB[j + 2];
                const int sn1 = sB[(j + 3 < m) ? (j + 3) : (j + 2)];
                const float2 v0 = *(const float2*)(g + (size_t)sn0 * HC + 4 * q);
                const float2 v1 = *(const float2*)(g + (size_t)sn1 * HC + 4 * q);
                const float e0 = eB[j + 0];
                const float e1 = eB[j + 1];
                const float2 a0 = __half22float2(*(const __half2*)&w0.x);
                const float2 a1 = __half22float2(*(const __half2*)&w0.y);
                const float2 b0 = __half22float2(*(const __half2*)&w1.x);
                const float2 b1 = __half22float2(*(const __half2*)&w1.y);
                acc.x = fmaf(e0, a0.x, acc.x); acc.y = fmaf(e0, a0.y, acc.y);
                acc.z = fmaf(e0, a1.x, acc.z); acc.w = fmaf(e0, a1.y, acc.w);
                acc.x = fmaf(e1, b0.x, acc.x); acc.y = fmaf(e1, b0.y, acc.y);
                acc.z = fmaf(e1, b1.x, acc.z); acc.w = fmaf(e1, b1.y, acc.w);
                w0 = v0; w1 = v1;
            }
            {
                const float e0 = eB[j];
                const float e1 = (j + 1 < m) ? eB[j + 1] : 0.f;
                const float2 a0 = __half22float2(*(const __half2*)&w0.x);
                const float2 a1 = __half22float2(*(const __half2*)&w0.y);
                const float2 b0 = __half22float2(*(const __half2*)&w1.x);
                const float2 b1 = __half22float2(*(const __half2*)&w1.y);
                acc.x = fmaf(e0, a0.x, acc.x); acc.y = fmaf(e0, a0.y, acc.y);
                acc.z = fmaf(e0, a1.x, acc.z); acc.w = fmaf(e0, a1.y, acc.w);
                acc.x = fmaf(e1, b0.x, acc.x); acc.y = fmaf(e1, b0.y, acc.y);
                acc.z = fmaf(e1, b1.x, acc.z); acc.w = fmaf(e1, b1.y, acc.w);
            }
            __threadfence_block();
        }

        #pragma unroll
        for (int off = 8; off >= 1; off >>= 1)
            dpart += __shfl_xor(dpart, off, 64);
        const float rden = 1.f / (dpart + eself);

        if (q < 10) {
            float4 r;
            r.x = acc.x * rden + b2v.x;
            r.y = acc.y * rden + b2v.y;
            r.z = acc.z * rden + b2v.z;
            r.w = acc.w * rden + b2v.w;
            *(float4*)(out + (size_t)node * NCLASS + 4 * q) = r;
        }
    }
}

extern "C" void kernel_launch(void* const* d_in, const int* in_sizes, int n_in,
                              void* d_out, int out_size, void* d_ws, size_t ws_size,
                              hipStream_t stream)
{
    const float* x    = (const float*)d_in[0];
    const int*   ei   = (const int*)  d_in[1];
    const float* W1   = (const float*)d_in[2];
    const float* as1w = (const float*)d_in[3];
    const float* ad1w = (const float*)d_in[4];
    const float* b1   = (const float*)d_in[5];
    const float* gm   = (const float*)d_in[6];
    const float* bt   = (const float*)d_in[7];
    const float* mn   = (const float*)d_in[8];
    const float* vr   = (const float*)d_in[9];
    const float* W2   = (const float*)d_in[10];
    const float* as2w = (const float*)d_in[11];
    const float* ad2w = (const float*)d_in[12];
    const float* b2   = (const float*)d_in[13];

    const int n = in_sizes[0] / NFEAT;           // 100000
    const int E = in_sizes[1] / 2;               // 1600000
    const int* esrc = ei;
    const int* edst = ei + E;

    const int nbk = (n + 511) >> BK_SH;          // 196 buckets
    const int nw  = (E + CHUNK - 1) / CHUNK;     // 196 chunks

    float*  ws   = (float*)d_ws;
    __half* h1   = (__half*)ws;
    float*  a_s1 = ws   + (size_t)n * 32;
    float*  a_d1 = a_s1 + (size_t)n * 4;
    __half* gbuf = (__half*)(a_d1 + (size_t)n * 4);
    float*  a_s2 = a_d1 + (size_t)n * 4 + (size_t)n * 32;
    float*  a_d2 = a_s2 + n;
    int2*   pairs  = (int2*)(a_d2 + n);
    int*    csr    = (int*)(pairs + E);
    int*    rowptr = csr + E;
    int*    hist   = rowptr + n;
    int*    colsum = hist + (size_t)nw * nbk;
    int*    bstart = colsum + nbk;
    float*  outv = (float*)d_out;

    const int nblk = (n + 15) / 16;

    k_hist   <<<nw, 256, 0, stream>>>(edst, hist, E, nbk);
    k_colscan<<<nbk, 256, 0, stream>>>(hist, colsum, nbk, nw);
    k_bscan  <<<1, 256, 0, stream>>>(colsum, bstart, nbk, E);
    k_scatter<<<nw, 256, 0, stream>>>(esrc, edst, hist, bstart, pairs, E, nbk);
    k_build  <<<nbk, 256, 0, stream>>>(pairs, bstart, rowptr, csr, n, nbk);
    k_gemm1  <<<512, 256, 0, stream>>>(x, W1, as1w, ad1w, h1, a_s1, a_d1, n);
    k_agg1   <<<nblk, 256, 0, stream>>>(csr, rowptr, h1, a_s1, a_d1,
                                        b1, gm, bt, mn, vr,
                                        W2, as2w, ad2w, gbuf, a_s2, a_d2, n);
    k_agg2   <<<nblk, 256, 0, stream>>>(csr, rowptr, gbuf, a_s2, a_d2,
                                        b2, outv, n);
}

// Round 10
// 274.792 us; speedup vs baseline: 2.1619x; 1.0699x over previous
//
#include <hip/hip_runtime.h>
#include <hip/hip_bf16.h>
#include <hip/hip_fp16.h>

#define NFEAT  128
#define HC     64
#define HEADS  4
#define NHID   16
#define NCLASS 40
#define NEG    0.2f
#define BN_EPS 1e-5f

#define BK_SH   9          // 512 nodes per bucket
#define CHUNK   8192       // edges per histogram/scatter workgroup
#define STAGE   12288      // LDS staging capacity in k_build

typedef _Float16 half8_t __attribute__((ext_vector_type(8)));
typedef _Float16 half4_t __attribute__((ext_vector_type(4)));
typedef float    f32x4_t __attribute__((ext_vector_type(4)));

__device__ __forceinline__ float leaky(float a) { return (a > 0.f) ? a : NEG * a; }

// ---------------------------------------------------------------------------
// Kernel 1 (MFMA): h1 = x @ W1 via v_mfma_f32_16x16x32_f16.
// ---------------------------------------------------------------------------
__global__ __launch_bounds__(256) void k_gemm1(
    const float* __restrict__ x, const float* __restrict__ W1,
    const float* __restrict__ att_s, const float* __restrict__ att_d,
    __half* __restrict__ h1, float* __restrict__ as1, float* __restrict__ ad1,
    int n)
{
    const int wave = threadIdx.x >> 6, lane = threadIdx.x & 63;
    const int quad = lane >> 4, l16 = lane & 15;

    half8_t bfrag[4][4];
    #pragma unroll
    for (int ks = 0; ks < 4; ++ks)
        #pragma unroll
        for (int ct = 0; ct < 4; ++ct)
            #pragma unroll
            for (int j = 0; j < 8; ++j)
                bfrag[ks][ct][j] =
                    (_Float16)W1[(ks * 32 + quad * 8 + j) * HC + ct * 16 + l16];

    float avs[4], avd[4];
    #pragma unroll
    for (int ct = 0; ct < 4; ++ct) {
        avs[ct] = att_s[ct * 16 + l16];
        avd[ct] = att_d[ct * 16 + l16];
    }

    const int nslab = (n + 15) >> 4;
    for (int slab = blockIdx.x * 4 + wave; slab < nslab; slab += gridDim.x * 4) {
        const int rowbase = slab * 16;
        const int arow = min(rowbase + l16, n - 1);
        const float* xp = x + (size_t)arow * NFEAT;

        f32x4_t acc[4] = {{0.f,0.f,0.f,0.f},{0.f,0.f,0.f,0.f},
                          {0.f,0.f,0.f,0.f},{0.f,0.f,0.f,0.f}};
        #pragma unroll
        for (int ks = 0; ks < 4; ++ks) {
            const float4 xa = *(const float4*)(xp + ks * 32 + quad * 8);
            const float4 xb = *(const float4*)(xp + ks * 32 + quad * 8 + 4);
            half8_t af;
            af[0] = (_Float16)xa.x; af[1] = (_Float16)xa.y;
            af[2] = (_Float16)xa.z; af[3] = (_Float16)xa.w;
            af[4] = (_Float16)xb.x; af[5] = (_Float16)xb.y;
            af[6] = (_Float16)xb.z; af[7] = (_Float16)xb.w;
            #pragma unroll
            for (int ct = 0; ct < 4; ++ct)
                acc[ct] = __builtin_amdgcn_mfma_f32_16x16x32_f16(
                    af, bfrag[ks][ct], acc[ct], 0, 0, 0);
        }

        #pragma unroll
        for (int reg = 0; reg < 4; ++reg) {
            const int row = rowbase + quad * 4 + reg;
            const bool valid = row < n;

            float4 ps, pd;
            ps.x = acc[0][reg] * avs[0]; pd.x = acc[0][reg] * avd[0];
            ps.y = acc[1][reg] * avs[1]; pd.y = acc[1][reg] * avd[1];
            ps.z = acc[2][reg] * avs[2]; pd.z = acc[2][reg] * avd[2];
            ps.w = acc[3][reg] * avs[3]; pd.w = acc[3][reg] * avd[3];
            #pragma unroll
            for (int off = 8; off >= 1; off >>= 1) {
                ps.x += __shfl_xor(ps.x, off, 64); pd.x += __shfl_xor(pd.x, off, 64);
                ps.y += __shfl_xor(ps.y, off, 64); pd.y += __shfl_xor(pd.y, off, 64);
                ps.z += __shfl_xor(ps.z, off, 64); pd.z += __shfl_xor(pd.z, off, 64);
                ps.w += __shfl_xor(ps.w, off, 64); pd.w += __shfl_xor(pd.w, off, 64);
            }
            if (valid) {
                #pragma unroll
                for (int ct = 0; ct < 4; ++ct)
                    h1[(size_t)row * HC + ct * 16 + l16] =
                        __float2half_rn(acc[ct][reg]);
                if (l16 == 0) {
                    *(float4*)(as1 + (size_t)row * HEADS) = ps;
                    *(float4*)(ad1 + (size_t)row * HEADS) = pd;
                }
            }
        }
    }
}

// ---------------------------------------------------------------------------
// CSR build (locality-preserving, no global atomics, no memset)
// 512-thread blocks + int4 edge loads this round.
// ---------------------------------------------------------------------------
__global__ __launch_bounds__(512) void k_hist(
    const int* __restrict__ edst, int* __restrict__ hist, int E, int nbk)
{
    __shared__ int lh[256];
    const int w = blockIdx.x, t = threadIdx.x;
    for (int i = t; i < nbk; i += 512) lh[i] = 0;
    __syncthreads();
    const int lo = w * CHUNK, hi = min(E, lo + CHUNK);
    for (int e = lo + 4 * t; e < hi; e += 4 * 512) {
        const int4 d4 = *(const int4*)(edst + e);
        atomicAdd(&lh[d4.x >> BK_SH], 1);
        atomicAdd(&lh[d4.y >> BK_SH], 1);
        atomicAdd(&lh[d4.z >> BK_SH], 1);
        atomicAdd(&lh[d4.w >> BK_SH], 1);
    }
    __syncthreads();
    for (int i = t; i < nbk; i += 512) hist[(size_t)w * nbk + i] = lh[i];
}

__global__ __launch_bounds__(256) void k_colscan(
    int* __restrict__ hist, int* __restrict__ colsum, int nbk, int nw)
{
    __shared__ int wred[4];
    const int b = blockIdx.x, t = threadIdx.x;
    const int lane = t & 63, w = t >> 6;
    const int v = (t < nw) ? hist[(size_t)t * nbk + b] : 0;
    int sc = v;
    #pragma unroll
    for (int off = 1; off < 64; off <<= 1) {
        int u = __shfl_up(sc, off, 64);
        if (lane >= off) sc += u;
    }
    if (lane == 63) wred[w] = sc;
    __syncthreads();
    if (t == 0) { int a = 0; for (int i = 0; i < 4; ++i) { int xx = wred[i]; wred[i] = a; a += xx; } }
    __syncthreads();
    const int excl = sc - v + wred[w];
    if (t < nw) hist[(size_t)t * nbk + b] = excl;
    if (t == nw - 1) colsum[b] = excl + v;
}

__global__ __launch_bounds__(256) void k_bscan(
    const int* __restrict__ colsum, int* __restrict__ bstart, int nbk, int E)
{
    __shared__ int wred[4];
    const int t = threadIdx.x, lane = t & 63, w = t >> 6;
    const int v = (t < nbk) ? colsum[t] : 0;
    int sc = v;
    #pragma unroll
    for (int off = 1; off < 64; off <<= 1) {
        int u = __shfl_up(sc, off, 64);
        if (lane >= off) sc += u;
    }
    if (lane == 63) wred[w] = sc;
    __syncthreads();
    if (t == 0) { int a = 0; for (int i = 0; i < 4; ++i) { int xx = wred[i]; wred[i] = a; a += xx; } }
    __syncthreads();
    if (t < nbk) bstart[t] = sc - v + wred[w];
    if (t == 0) bstart[nbk] = E;
}

__global__ __launch_bounds__(512) void k_scatter(
    const int* __restrict__ esrc, const int* __restrict__ edst,
    const int* __restrict__ hist, const int* __restrict__ bstart,
    int2* __restrict__ pairs, int E, int nbk)
{
    __shared__ int cur[256];
    const int w = blockIdx.x, t = threadIdx.x;
    for (int i = t; i < nbk; i += 512)
        cur[i] = bstart[i] + hist[(size_t)w * nbk + i];
    __syncthreads();
    const int lo = w * CHUNK, hi = min(E, lo + CHUNK);
    for (int e = lo + 4 * t; e < hi; e += 4 * 512) {
        const int4 s4 = *(const int4*)(esrc + e);
        const int4 d4 = *(const int4*)(edst + e);
        int pos;
        pos = atomicAdd(&cur[d4.x >> BK_SH], 1); pairs[pos] = make_int2(s4.x, d4.x);
        pos = atomicAdd(&cur[d4.y >> BK_SH], 1); pairs[pos] = make_int2(s4.y, d4.y);
        pos = atomicAdd(&cur[d4.z >> BK_SH], 1); pairs[pos] = make_int2(s4.z, d4.z);
        pos = atomicAdd(&cur[d4.w >> BK_SH], 1); pairs[pos] = make_int2(s4.w, d4.w);
    }
}

__global__ __launch_bounds__(512) void k_build(
    const int2* __restrict__ pairs, const int* __restrict__ bstart,
    int* __restrict__ rowptr, int* __restrict__ csr, int n, int nbk)
{
    __shared__ int cnt[512];
    __shared__ int cur[512];
    __shared__ int stage[STAGE];
    __shared__ int wred[8];
    const int b = blockIdx.x, t = threadIdx.x;
    const int base = bstart[b], eend = bstart[b + 1], m = eend - base;
    const int n0 = b << BK_SH;
    const int nn = min(512, n - n0);

    cnt[t] = 0;
    __syncthreads();
    for (int e = base + t; e < eend; e += 512)
        atomicAdd(&cnt[pairs[e].y - n0], 1);
    __syncthreads();

    // 512-thread exclusive scan: wave scans + wave-sum scan
    const int v = cnt[t];
    const int lane = t & 63, w = t >> 6;
    int sc = v;
    #pragma unroll
    for (int off = 1; off < 64; off <<= 1) {
        int u = __shfl_up(sc, off, 64);
        if (lane >= off) sc += u;
    }
    if (lane == 63) wred[w] = sc;
    __syncthreads();
    if (t == 0) { int a = 0; for (int i = 0; i < 8; ++i) { int xx = wred[i]; wred[i] = a; a += xx; } }
    __syncthreads();
    const int excl = sc - v + wred[w];
    cur[t] = excl;
    if (t < nn) rowptr[n0 + t] = base + excl + v;   // inclusive end of node n0+t
    __syncthreads();

    for (int e = base + t; e < eend; e += 512) {
        const int2 p = pairs[e];
        const int loc = atomicAdd(&cur[p.y - n0], 1);
        if (loc < STAGE) stage[loc] = p.x;
        else             csr[base + loc] = p.x;
    }
    __syncthreads();
    const int lim = min(m, STAGE);
    for (int i = t; i < lim; i += 512) csr[base + i] = stage[i];
}

// ---------------------------------------------------------------------------
// Kernel agg1: one 16-lane group per node (identity order).
// fp16 W2 in LDS, software-pipelined gather loop.
// ---------------------------------------------------------------------------
__global__ __launch_bounds__(256) void k_agg1(
    const int* __restrict__ csr, const int* __restrict__ rowptr,
    const __half* __restrict__ h1, const float* __restrict__ as1,
    const float* __restrict__ ad1,
    const float* __restrict__ bias1, const float* __restrict__ gamma,
    const float* __restrict__ beta, const float* __restrict__ mean,
    const float* __restrict__ var,
    const float* __restrict__ W2, const float* __restrict__ ats2,
    const float* __restrict__ atd2,
    __half* __restrict__ g, float* __restrict__ as2o, float* __restrict__ ad2o,
    int n)
{
    __shared__ _Float16 sWh[NCLASS * HC];  // 5 KB, [k][c]
    __shared__ float sh[16][68];
    __shared__ float sE[16][132];
    __shared__ int   sS[16][33];
    for (int i = threadIdx.x; i < NCLASS * HC; i += 256) sWh[i] = (_Float16)W2[i];
    __syncthreads();

    const int gi = threadIdx.x >> 4;
    const int q  = threadIdx.x & 15;
    const int myh = q >> 2;

    const float4 b1v = *(const float4*)(bias1 + 4 * q);
    const float4 gmv = *(const float4*)(gamma + 4 * q);
    const float4 vrv = *(const float4*)(var   + 4 * q);
    const float4 mnv = *(const float4*)(mean  + 4 * q);
    const float4 btv = *(const float4*)(beta  + 4 * q);
    float4 scv, shv;
    scv.x = gmv.x * rsqrtf(vrv.x + BN_EPS);
    scv.y = gmv.y * rsqrtf(vrv.y + BN_EPS);
    scv.z = gmv.z * rsqrtf(vrv.z + BN_EPS);
    scv.w = gmv.w * rsqrtf(vrv.w + BN_EPS);
    shv.x = btv.x - mnv.x * scv.x;
    shv.y = btv.y - mnv.y * scv.y;
    shv.z = btv.z - mnv.z * scv.z;
    shv.w = btv.w - mnv.w * scv.w;
    float4 at2 = {0.f, 0.f, 0.f, 0.f}, dt2 = {0.f, 0.f, 0.f, 0.f};
    if (q < 10) {
        at2 = *(const float4*)(ats2 + 4 * q);
        dt2 = *(const float4*)(atd2 + 4 * q);
    }

    for (int node0 = blockIdx.x * 16; node0 < n; node0 += gridDim.x * 16) {
        const int node = node0 + gi;
        if (node >= n) continue;

        const float4 adv = *(const float4*)(ad1 + node * HEADS);
        const float4 sv4 = *(const float4*)(as1 + node * HEADS);
        float4 eself;
        eself.x = __expf(leaky(sv4.x + adv.x));
        eself.y = __expf(leaky(sv4.y + adv.y));
        eself.z = __expf(leaky(sv4.z + adv.z));
        eself.w = __expf(leaky(sv4.w + adv.w));
        const float es = (myh == 0) ? eself.x : (myh == 1) ? eself.y
                       : (myh == 2) ? eself.z : eself.w;

        float2 raws = *(const float2*)(h1 + (size_t)node * HC + 4 * q);
        const float2 s0v = __half22float2(*(__half2*)&raws.x);
        const float2 s1v = __half22float2(*(__half2*)&raws.y);
        float4 acc;
        acc.x = es * s0v.x; acc.y = es * s0v.y;
        acc.z = es * s1v.x; acc.w = es * s1v.y;
        float4 dpart = {0.f, 0.f, 0.f, 0.f};

        const int start = (node == 0) ? 0 : rowptr[node - 1];
        const int end   = rowptr[node];

        for (int base = start; base < end; base += 32) {
            const int m = min(32, end - base);
            float4 ea = {0.f, 0.f, 0.f, 0.f}, eb = {0.f, 0.f, 0.f, 0.f};
            int ia = 0, ib = 0;
            if (q < m) {
                ia = csr[base + q];
                const float4 s4 = *(const float4*)(as1 + (size_t)ia * HEADS);
                ea.x = __expf(leaky(s4.x + adv.x));
                ea.y = __expf(leaky(s4.y + adv.y));
                ea.z = __expf(leaky(s4.z + adv.z));
                ea.w = __expf(leaky(s4.w + adv.w));
            }
            if (q + 16 < m) {
                ib = csr[base + q + 16];
                const float4 s4 = *(const float4*)(as1 + (size_t)ib * HEADS);
                eb.x = __expf(leaky(s4.x + adv.x));
                eb.y = __expf(leaky(s4.y + adv.y));
                eb.z = __expf(leaky(s4.z + adv.z));
                eb.w = __expf(leaky(s4.w + adv.w));
            }
            dpart.x += ea.x + eb.x; dpart.y += ea.y + eb.y;
            dpart.z += ea.z + eb.z; dpart.w += ea.w + eb.w;
            *(float4*)&sE[gi][4 * q] = ea;
            *(float4*)&sE[gi][4 * (q + 16)] = eb;
            sS[gi][q] = ia; sS[gi][q + 16] = ib;
            __threadfence_block();

            const int*   sB = &sS[gi][0];
            const float* eB = &sE[gi][0];
            int j = 0;
            const int sa0 = sB[0];
            const int sa1 = sB[(m > 1) ? 1 : 0];
            float2 w0 = *(const float2*)(h1 + (size_t)sa0 * HC + 4 * q);
            float2 w1 = *(const float2*)(h1 + (size_t)sa1 * HC + 4 * q);
            for (; j + 2 < m; j += 2) {
                const int sn0 = sB[j + 2];
                const int sn1 = sB[(j + 3 < m) ? (j + 3) : (j + 2)];
                const float2 v0 = *(const float2*)(h1 + (size_t)sn0 * HC + 4 * q);
                const float2 v1 = *(const float2*)(h1 + (size_t)sn1 * HC + 4 * q);
                const float e0 = eB[(j + 0) * 4 + myh];
                const float e1 = eB[(j + 1) * 4 + myh];
                const float2 a0 = __half22float2(*(const __half2*)&w0.x);
                const float2 a1 = __half22float2(*(const __half2*)&w0.y);
                const float2 b0 = __half22float2(*(const __half2*)&w1.x);
                const float2 b1 = __half22float2(*(const __half2*)&w1.y);
                acc.x = fmaf(e0, a0.x, acc.x); acc.y = fmaf(e0, a0.y, acc.y);
                acc.z = fmaf(e0, a1.x, acc.z); acc.w = fmaf(e0, a1.y, acc.w);
                acc.x = fmaf(e1, b0.x, acc.x); acc.y = fmaf(e1, b0.y, acc.y);
                acc.z = fmaf(e1, b1.x, acc.z); acc.w = fmaf(e1, b1.y, acc.w);
                w0 = v0; w1 = v1;
            }
            {
                const float e0 = eB[j * 4 + myh];
                const float e1 = (j + 1 < m) ? eB[(j + 1) * 4 + myh] : 0.f;
                const float2 a0 = __half22float2(*(const __half2*)&w0.x);
                const float2 a1 = __half22float2(*(const __half2*)&w0.y);
                const float2 b0 = __half22float2(*(const __half2*)&w1.x);
                const float2 b1 = __half22float2(*(const __half2*)&w1.y);
                acc.x = fmaf(e0, a0.x, acc.x); acc.y = fmaf(e0, a0.y, acc.y);
                acc.z = fmaf(e0, a1.x, acc.z); acc.w = fmaf(e0, a1.y, acc.w);
                acc.x = fmaf(e1, b0.x, acc.x); acc.y = fmaf(e1, b0.y, acc.y);
                acc.z = fmaf(e1, b1.x, acc.z); acc.w = fmaf(e1, b1.y, acc.w);
            }
            __threadfence_block();
        }

        #pragma unroll
        for (int off = 8; off >= 1; off >>= 1) {
            dpart.x += __shfl_xor(dpart.x, off, 64);
            dpart.y += __shfl_xor(dpart.y, off, 64);
            dpart.z += __shfl_xor(dpart.z, off, 64);
            dpart.w += __shfl_xor(dpart.w, off, 64);
        }
        const float den = es + ((myh == 0) ? dpart.x : (myh == 1) ? dpart.y
                               : (myh == 2) ? dpart.z : dpart.w);
        const float rden = 1.f / den;

        float4 v;
        v.x = fmaxf(fmaf(acc.x * rden + b1v.x, scv.x, shv.x), 0.f);
        v.y = fmaxf(fmaf(acc.y * rden + b1v.y, scv.y, shv.y), 0.f);
        v.z = fmaxf(fmaf(acc.z * rden + b1v.z, scv.z, shv.z), 0.f);
        v.w = fmaxf(fmaf(acc.w * rden + b1v.w, scv.w, shv.w), 0.f);
        *(float4*)&sh[gi][4 * q] = v;
        __threadfence_block();

        float4 gacc = {0.f, 0.f, 0.f, 0.f};
        if (q < 10) {
            #pragma unroll 8
            for (int k = 0; k < HC; ++k) {
                const float hk = sh[gi][k];
                const half4_t wv = *(const half4_t*)&sWh[k * NCLASS + 4 * q];
                gacc.x = fmaf(hk, (float)wv[0], gacc.x);
                gacc.y = fmaf(hk, (float)wv[1], gacc.y);
                gacc.z = fmaf(hk, (float)wv[2], gacc.z);
                gacc.w = fmaf(hk, (float)wv[3], gacc.w);
            }
        }
        __half2 p0 = __float22half2_rn({gacc.x, gacc.y});
        __half2 p1 = __float22half2_rn({gacc.z, gacc.w});
        float2 packed; *(__half2*)&packed.x = p0; *(__half2*)&packed.y = p1;
        *(float2*)(g + (size_t)node * HC + 4 * q) = packed;

        float sv = gacc.x * at2.x + gacc.y * at2.y + gacc.z * at2.z + gacc.w * at2.w;
        float dv = gacc.x * dt2.x + gacc.y * dt2.y + gacc.z * dt2.z + gacc.w * dt2.w;
        #pragma unroll
        for (int off = 8; off >= 1; off >>= 1) {
            sv += __shfl_xor(sv, off, 64);
            dv += __shfl_xor(dv, off, 64);
        }
        if (q == 0) { as2o[node] = sv; ad2o[node] = dv; }
        __threadfence_block();
    }
}

// ---------------------------------------------------------------------------
// Kernel agg2: one 16-lane group per node (identity order), pipelined gathers.
// ---------------------------------------------------------------------------
__global__ __launch_bounds__(256) void k_agg2(
    const int* __restrict__ csr, const int* __restrict__ rowptr,
    const __half* __restrict__ g, const float* __restrict__ as2,
    const float* __restrict__ ad2, const float* __restrict__ bias2,
    float* __restrict__ out, int n)
{
    __shared__ float sE[16][34];
    __shared__ int   sS[16][33];
    const int gi = threadIdx.x >> 4;
    const int q  = threadIdx.x & 15;

    float4 b2v = {0.f, 0.f, 0.f, 0.f};
    if (q < 10) b2v = *(const float4*)(bias2 + 4 * q);

    for (int node0 = blockIdx.x * 16; node0 < n; node0 += gridDim.x * 16) {
        const int node = node0 + gi;
        if (node >= n) continue;

        const float ad2d = ad2[node];
        const float eself = __expf(leaky(as2[node] + ad2d));

        float2 raws = *(const float2*)(g + (size_t)node * HC + 4 * q);
        const float2 s0v = __half22float2(*(__half2*)&raws.x);
        const float2 s1v = __half22float2(*(__half2*)&raws.y);
        float4 acc;
        acc.x = eself * s0v.x; acc.y = eself * s0v.y;
        acc.z = eself * s1v.x; acc.w = eself * s1v.y;
        float dpart = 0.f;

        const int start = (node == 0) ? 0 : rowptr[node - 1];
        const int end   = rowptr[node];

        for (int base = start; base < end; base += 32) {
            const int m = min(32, end - base);
            float ea = 0.f, eb = 0.f;
            int ia = 0, ib = 0;
            if (q < m) {
                ia = csr[base + q];
                ea = __expf(leaky(as2[ia] + ad2d));
            }
            if (q + 16 < m) {
                ib = csr[base + q + 16];
                eb = __expf(leaky(as2[ib] + ad2d));
            }
            dpart += ea + eb;
            sE[gi][q] = ea; sE[gi][q + 16] = eb;
            sS[gi][q] = ia; sS[gi][q + 16] = ib;
            __threadfence_block();

            const int*   sB = &sS[gi][0];
            const float* eB = &sE[gi][0];
            int j = 0;
            const int sa0 = sB[0];
            const int sa1 = sB[(m > 1) ? 1 : 0];
            float2 w0 = *(const float2*)(g + (size_t)sa0 * HC + 4 * q);
            float2 w1 = *(const float2*)(g + (size_t)sa1 * HC + 4 * q);
            for (; j + 2 < m; j += 2) {
                const int sn0 = sB[j + 2];
                const int sn1 = sB[(j + 3 < m) ? (j + 3) : (j + 2)];
                const float2 v0 = *(const float2*)(g + (size_t)sn0 * HC + 4 * q);
                const float2 v1 = *(const float2*)(g + (size_t)sn1 * HC + 4 * q);
                const float e0 = eB[j + 0];
                const float e1 = eB[j + 1];
                const float2 a0 = __half22float2(*(const __half2*)&w0.x);
                const float2 a1 = __half22float2(*(const __half2*)&w0.y);
                const float2 b0 = __half22float2(*(const __half2*)&w1.x);
                const float2 b1 = __half22float2(*(const __half2*)&w1.y);
                acc.x = fmaf(e0, a0.x, acc.x); acc.y = fmaf(e0, a0.y, acc.y);
                acc.z = fmaf(e0, a1.x, acc.z); acc.w = fmaf(e0, a1.y, acc.w);
                acc.x = fmaf(e1, b0.x, acc.x); acc.y = fmaf(e1, b0.y, acc.y);
                acc.z = fmaf(e1, b1.x, acc.z); acc.w = fmaf(e1, b1.y, acc.w);
                w0 = v0; w1 = v1;
            }
            {
                const float e0 = eB[j];
                const float e1 = (j + 1 < m) ? eB[j + 1] : 0.f;
                const float2 a0 = __half22float2(*(const __half2*)&w0.x);
                const float2 a1 = __half22float2(*(const __half2*)&w0.y);
                const float2 b0 = __half22float2(*(const __half2*)&w1.x);
                const float2 b1 = __half22float2(*(const __half2*)&w1.y);
                acc.x = fmaf(e0, a0.x, acc.x); acc.y = fmaf(e0, a0.y, acc.y);
                acc.z = fmaf(e0, a1.x, acc.z); acc.w = fmaf(e0, a1.y, acc.w);
                acc.x = fmaf(e1, b0.x, acc.x); acc.y = fmaf(e1, b0.y, acc.y);
                acc.z = fmaf(e1, b1.x, acc.z); acc.w = fmaf(e1, b1.y, acc.w);
            }
            __threadfence_block();
        }

        #pragma unroll
        for (int off = 8; off >= 1; off >>= 1)
            dpart += __shfl_xor(dpart, off, 64);
        const float rden = 1.f / (dpart + eself);

        if (q < 10) {
            float4 r;
            r.x = acc.x * rden + b2v.x;
            r.y = acc.y * rden + b2v.y;
            r.z = acc.z * rden + b2v.z;
            r.w = acc.w * rden + b2v.w;
            *(float4*)(out + (size_t)node * NCLASS + 4 * q) = r;
        }
    }
}

extern "C" void kernel_launch(void* const* d_in, const int* in_sizes, int n_in,
                              void* d_out, int out_size, void* d_ws, size_t ws_size,
                              hipStream_t stream)
{
    const float* x    = (const float*)d_in[0];
    const int*   ei   = (const int*)  d_in[1];
    const float* W1   = (const float*)d_in[2];
    const float* as1w = (const float*)d_in[3];
    const float* ad1w = (const float*)d_in[4];
    const float* b1   = (const float*)d_in[5];
    const float* gm   = (const float*)d_in[6];
    const float* bt   = (const float*)d_in[7];
    const float* mn   = (const float*)d_in[8];
    const float* vr   = (const float*)d_in[9];
    const float* W2   = (const float*)d_in[10];
    const float* as2w = (const float*)d_in[11];
    const float* ad2w = (const float*)d_in[12];
    const float* b2   = (const float*)d_in[13];

    const int n = in_sizes[0] / NFEAT;           // 100000
    const int E = in_sizes[1] / 2;               // 1600000
    const int* esrc = ei;
    const int* edst = ei + E;

    const int nbk = (n + 511) >> BK_SH;          // 196 buckets
    const int nw  = (E + CHUNK - 1) / CHUNK;     // 196 chunks

    float*  ws   = (float*)d_ws;
    __half* h1   = (__half*)ws;
    float*  a_s1 = ws   + (size_t)n * 32;
    float*  a_d1 = a_s1 + (size_t)n * 4;
    __half* gbuf = (__half*)(a_d1 + (size_t)n * 4);
    float*  a_s2 = a_d1 + (size_t)n * 4 + (size_t)n * 32;
    float*  a_d2 = a_s2 + n;
    int2*   pairs  = (int2*)(a_d2 + n);
    int*    csr    = (int*)(pairs + E);
    int*    rowptr = csr + E;
    int*    hist   = rowptr + n;
    int*    colsum = hist + (size_t)nw * nbk;
    int*    bstart = colsum + nbk;
    float*  outv = (float*)d_out;

    const int nblk = (n + 15) / 16;

    k_hist   <<<nw, 512, 0, stream>>>(edst, hist, E, nbk);
    k_colscan<<<nbk, 256, 0, stream>>>(hist, colsum, nbk, nw);
    k_bscan  <<<1, 256, 0, stream>>>(colsum, bstart, nbk, E);
    k_scatter<<<nw, 512, 0, stream>>>(esrc, edst, hist, bstart, pairs, E, nbk);
    k_build  <<<nbk, 512, 0, stream>>>(pairs, bstart, rowptr, csr, n, nbk);
    k_gemm1  <<<512, 256, 0, stream>>>(x, W1, as1w, ad1w, h1, a_s1, a_d1, n);
    k_agg1   <<<nblk, 256, 0, stream>>>(csr, rowptr, h1, a_s1, a_d1,
                                        b1, gm, bt, mn, vr,
                                        W2, as2w, ad2w, gbuf, a_s2, a_d2, n);
    k_agg2   <<<nblk, 256, 0, stream>>>(csr, rowptr, gbuf, a_s2, a_d2,
                                        b2, outv, n);
}